// Round 9
// baseline (1174.347 us; speedup 1.0000x reference)
//
#include <hip/hip_runtime.h>

typedef __attribute__((ext_vector_type(8))) short bf16x8;
typedef __attribute__((ext_vector_type(4))) short bf16x4;
typedef __attribute__((ext_vector_type(2))) short bf16x2;
typedef __attribute__((ext_vector_type(4))) float f32x4;

#define D_MODEL 512
#define N_HEADS 8
#define HEAD_DIM 64
#define SEQ_C 1024
#define SEQ_P 512
#define BATCH 8
#define FFDIM 2048
#define VOCAB 70
#define NLAYER 4
#define MQ (BATCH*SEQ_C)    /* 8192 */
#define MKV (BATCH*SEQ_P)   /* 4096 */
#define KSTR 72             /* flash LDS row stride in bf16 units */
#define SCALE2 0.18033688011112043f   /* 0.125 * log2(e) */

__device__ __forceinline__ short f2bs(float f) {   // f32 -> bf16 bits, RNE
  union { float f; unsigned u; } v; v.f = f;
  unsigned r = (v.u + 0x7FFFu + ((v.u >> 16) & 1u)) >> 16;
  return (short)r;
}

__device__ __forceinline__ float bs2f(short s) {   // bf16 bits -> f32
  union { float f; unsigned u; } v;
  v.u = ((unsigned)(unsigned short)s) << 16;
  return v.f;
}

__device__ __forceinline__ void gl_lds16(const void* g, void* l) {
  __builtin_amdgcn_global_load_lds(
      (const __attribute__((address_space(1))) void*)g,
      (__attribute__((address_space(3))) void*)l, 16, 0, 0);
}

// ---------------- embedding: bf16 residual stream only ----------------
__global__ __launch_bounds__(256)
void embed_kernel(const int* __restrict__ cds, const float* __restrict__ tok,
                  const float* __restrict__ pos, short* __restrict__ xb) {
  int idx = (blockIdx.x * 256 + threadIdx.x) * 4;
  int row = idx >> 9, c = idx & 511;
  int l = row & (SEQ_C - 1);
  int t = cds[row];
  float4 tv = *(const float4*)(tok + (size_t)t * D_MODEL + c);
  float4 pv = *(const float4*)(pos + (size_t)l * D_MODEL + c);
  bf16x4 o;
  o[0] = f2bs(tv.x * 22.627416997969522f + pv.x);
  o[1] = f2bs(tv.y * 22.627416997969522f + pv.y);
  o[2] = f2bs(tv.z * 22.627416997969522f + pv.z);
  o[3] = f2bs(tv.w * 22.627416997969522f + pv.w);
  *(bf16x4*)(xb + idx) = o;
}

// fp32 -> bf16 bulk convert (enc_prot)
__global__ __launch_bounds__(256)
void cvtf2b_kernel(const float* __restrict__ in, short* __restrict__ out) {
  int i = (blockIdx.x * 256 + threadIdx.x) * 4;
  float4 v = *(const float4*)(in + i);
  bf16x4 o;
  o[0] = f2bs(v.x); o[1] = f2bs(v.y); o[2] = f2bs(v.z); o[3] = f2bs(v.w);
  *(bf16x4*)(out + i) = o;
}

// ---- merged 8-way square (512x512) weight transpose, grid z = 8*NLAYER ----
struct WtArgs {
  const float* src[8];
  short* dst[8];
  size_t ldz[8];
  int row_off[8];
};

__global__ __launch_bounds__(256)
void wtrans8_kernel(WtArgs a) {
  __shared__ float T[32][33];
  int z = blockIdx.z;
  int job = z >> 2, layer = z & 3;
  const float* W = a.src[job] + (size_t)layer * D_MODEL * D_MODEL;
  short* Wt = a.dst[job] + (size_t)layer * a.ldz[job];
  int row_off = a.row_off[job];
  int n0 = blockIdx.x * 32, k0 = blockIdx.y * 32;
  int r = threadIdx.x >> 3, c4 = (threadIdx.x & 7) * 4;
  float4 v = *(const float4*)(W + (size_t)(k0 + r) * D_MODEL + n0 + c4);
  T[c4 + 0][r] = v.x; T[c4 + 1][r] = v.y; T[c4 + 2][r] = v.z; T[c4 + 3][r] = v.w;
  __syncthreads();
  bf16x4 o;
  o[0] = f2bs(T[r][c4 + 0]); o[1] = f2bs(T[r][c4 + 1]);
  o[2] = f2bs(T[r][c4 + 2]); o[3] = f2bs(T[r][c4 + 3]);
  *(bf16x4*)&Wt[(size_t)(row_off + n0 + r) * D_MODEL + k0 + c4] = o;
}

// W [K,N] fp32 -> Wt [N,K] bf16, per-layer via blockIdx.z (FFN weights)
__global__ __launch_bounds__(256)
void wtrans_kernel(const float* __restrict__ W, short* __restrict__ Wt,
                   int K, int N, size_t dst_ldz) {
  __shared__ float T[32][33];
  size_t lo_s = (size_t)blockIdx.z * K * N;
  size_t lo_d = (size_t)blockIdx.z * dst_ldz;
  int n0 = blockIdx.x * 32, k0 = blockIdx.y * 32;
  int r = threadIdx.x >> 3, c4 = (threadIdx.x & 7) * 4;
  float4 v = *(const float4*)(W + lo_s + (size_t)(k0 + r) * N + n0 + c4);
  T[c4 + 0][r] = v.x; T[c4 + 1][r] = v.y; T[c4 + 2][r] = v.z; T[c4 + 3][r] = v.w;
  __syncthreads();
  bf16x4 o;
  o[0] = f2bs(T[r][c4 + 0]); o[1] = f2bs(T[r][c4 + 1]);
  o[2] = f2bs(T[r][c4 + 2]); o[3] = f2bs(T[r][c4 + 3]);
  *(bf16x4*)&Wt[lo_d + (size_t)(n0 + r) * K + k0 + c4] = o;
}

// fc_out_w [512,70] -> padded bf16 [128][512] (rows >= 70 zero)
__global__ __launch_bounds__(256)
void logits_wt_kernel(const float* __restrict__ w, short* __restrict__ wt) {
  int idx = blockIdx.x * 256 + threadIdx.x;
  int r = idx >> 9, c = idx & 511;
  wt[idx] = (r < VOCAB) ? f2bs(w[c * VOCAB + r]) : (short)0;
}

// =======================================================================
// bf16 MFMA GEMM, MT x 128 tile, BK=32, 4 waves, 2-phase double-buffered.
// OMODE: 0 fp32 out; 1 bf16 out; 2 bf16 segment-split; 3 fp32 guarded.
// KSPLIT: blockIdx.z halves K; z=0 -> Cf (+bias), z=1 -> Cf2 (no bias).
// =======================================================================
template<int ACT, int OMODE, int MT, int KSPLIT = 0>
__global__ __launch_bounds__(256)
void gemm_mfma(const short* __restrict__ Ab, const short* __restrict__ Wt,
               const float* __restrict__ b0, const float* __restrict__ b1,
               const float* __restrict__ b2,
               float* __restrict__ Cf, float* __restrict__ Cf2,
               short* __restrict__ Cb,
               int N, int K, int ldc, size_t segstride) {
  constexpr int MREP = MT / 32;
  __shared__ __align__(16) short As[2][MT * 32];
  __shared__ __align__(16) short Bs[2][4096];
  int tid = threadIdx.x, lane = tid & 63, w = tid >> 6;
  int quad = lane >> 4, ln = lane & 15;
  int row0 = blockIdx.x * MT, col0 = blockIdx.y * 128;
  int kz = KSPLIT ? (int)blockIdx.z : 0;
  int Keff = KSPLIT ? (K >> 1) : K;
  int koff = kz * Keff;
  int q0 = tid, q1 = tid + 256;
  const short* a0 = Ab + (size_t)(row0 + (q0 >> 2)) * K + koff + (q0 & 3) * 8;
  const short* a1 = Ab + (size_t)(row0 + (q1 >> 2)) * K + koff + (q1 & 3) * 8;
  const short* w0 = Wt + (size_t)(col0 + (q0 >> 2)) * K + koff + (q0 & 3) * 8;
  const short* w1 = Wt + (size_t)(col0 + (q1 >> 2)) * K + koff + (q1 & 3) * 8;
  int wr = (w >> 1) * (MT / 2), wc = (w & 1) * 64;
  f32x4 acc[MREP][4];
  #pragma unroll
  for (int mb = 0; mb < MREP; mb++)
    #pragma unroll
    for (int nb = 0; nb < 4; nb++) acc[mb][nb] = (f32x4){0.f, 0.f, 0.f, 0.f};

  int nt = Keff >> 5;
#define STG(ko, buf) do { \
    gl_lds16(a0 + (ko), &As[buf][w * 512]); \
    if (MT == 128) gl_lds16(a1 + (ko), &As[buf][MT * 16 + w * 512]); \
    gl_lds16(w0 + (ko), &Bs[buf][w * 512]); \
    gl_lds16(w1 + (ko), &Bs[buf][2048 + w * 512]); } while (0)

  STG(0, 0);
  __syncthreads();
  for (int t = 0; t < nt; t++) {
    int cur = t & 1;
    if (t + 1 < nt) STG((t + 1) << 5, cur ^ 1);
    bf16x8 af[MREP], bfr[4];
    #pragma unroll
    for (int i = 0; i < MREP; i++)
      af[i] = *(const bf16x8*)&As[cur][(wr + i * 16 + ln) * 32 + quad * 8];
    #pragma unroll
    for (int i = 0; i < 4; i++)
      bfr[i] = *(const bf16x8*)&Bs[cur][(wc + i * 16 + ln) * 32 + quad * 8];
    #pragma unroll
    for (int mb = 0; mb < MREP; mb++)
      #pragma unroll
      for (int nb = 0; nb < 4; nb++)
        acc[mb][nb] = __builtin_amdgcn_mfma_f32_16x16x32_bf16(
            af[mb], bfr[nb], acc[mb][nb], 0, 0, 0);
    __syncthreads();
  }
#undef STG

  int colb = col0 + wc;
  const float* bp = b0;
  if (OMODE == 2) {
    int seg = colb >> 9;
    bp = (seg == 0) ? b0 : (seg == 1) ? b1 : b2;
  }
  float bv[4];
  #pragma unroll
  for (int nb = 0; nb < 4; nb++) {
    int col = colb + nb * 16 + ln;
    if (KSPLIT && kz)    bv[nb] = 0.f;
    else if (OMODE == 3) bv[nb] = (col < ldc) ? bp[col] : 0.f;
    else if (OMODE == 2) bv[nb] = bp[col & 511];
    else                 bv[nb] = bp[col];
  }
  float* Co = (KSPLIT && kz) ? Cf2 : Cf;
  size_t segoff = (OMODE == 2) ? (size_t)(colb >> 9) * segstride : 0;
  #pragma unroll
  for (int mb = 0; mb < MREP; mb++)
    #pragma unroll
    for (int i = 0; i < 4; i++) {
      size_t r = (size_t)(row0 + wr + mb * 16 + quad * 4 + i);
      #pragma unroll
      for (int nb = 0; nb < 4; nb++) {
        int col = colb + nb * 16 + ln;
        float v = acc[mb][nb][i] + bv[nb];
        if (ACT) v = fmaxf(v, 0.f);
        if (OMODE == 0)      Co[r * ldc + col] = v;
        else if (OMODE == 1) Cb[r * ldc + col] = f2bs(v);
        else if (OMODE == 2) Cb[segoff + r * 512 + (col & 511)] = f2bs(v);
        else if (col < ldc)  Co[r * ldc + col] = v;
      }
    }
}

// =======================================================================
// Mega launch: SA-QKV (768 blocks) + CA-KV (256 blocks), both MT=128, K=512.
// =======================================================================
__global__ __launch_bounds__(256)
void gemm_mega(const short* __restrict__ A0, const short* __restrict__ W0,
               const float* __restrict__ bq, const float* __restrict__ bk,
               const float* __restrict__ bv0, short* __restrict__ out0,
               const short* __restrict__ A1, const short* __restrict__ W1,
               const float* __restrict__ bk2, const float* __restrict__ bv2,
               short* __restrict__ out1) {
  __shared__ __align__(16) short As[2][4096];
  __shared__ __align__(16) short Bs[2][4096];
  const int K = 512;
  int bid = blockIdx.x;
  int job = bid >= 768;
  const short* Ab; const short* Wt; int row0, col0;
  if (!job) { Ab = A0; Wt = W0; row0 = (bid & 63) << 7; col0 = (bid >> 6) << 7; }
  else { int b2 = bid - 768; Ab = A1; Wt = W1; row0 = (b2 & 31) << 7; col0 = (b2 >> 5) << 7; }
  int tid = threadIdx.x, lane = tid & 63, w = tid >> 6;
  int quad = lane >> 4, ln = lane & 15;
  int q0 = tid, q1 = tid + 256;
  const short* a0 = Ab + (size_t)(row0 + (q0 >> 2)) * K + (q0 & 3) * 8;
  const short* a1 = Ab + (size_t)(row0 + (q1 >> 2)) * K + (q1 & 3) * 8;
  const short* w0 = Wt + (size_t)(col0 + (q0 >> 2)) * K + (q0 & 3) * 8;
  const short* w1 = Wt + (size_t)(col0 + (q1 >> 2)) * K + (q1 & 3) * 8;
  int wr = (w >> 1) * 64, wc = (w & 1) * 64;
  f32x4 acc[4][4];
  #pragma unroll
  for (int mb = 0; mb < 4; mb++)
    #pragma unroll
    for (int nb = 0; nb < 4; nb++) acc[mb][nb] = (f32x4){0.f, 0.f, 0.f, 0.f};

#define STG(ko, buf) do { \
    gl_lds16(a0 + (ko), &As[buf][w * 512]); \
    gl_lds16(a1 + (ko), &As[buf][2048 + w * 512]); \
    gl_lds16(w0 + (ko), &Bs[buf][w * 512]); \
    gl_lds16(w1 + (ko), &Bs[buf][2048 + w * 512]); } while (0)

  STG(0, 0);
  __syncthreads();
  for (int t = 0; t < 16; t++) {
    int cur = t & 1;
    if (t + 1 < 16) STG((t + 1) << 5, cur ^ 1);
    bf16x8 af[4], bfr[4];
    #pragma unroll
    for (int i = 0; i < 4; i++) {
      af[i]  = *(const bf16x8*)&As[cur][(wr + i * 16 + ln) * 32 + quad * 8];
      bfr[i] = *(const bf16x8*)&Bs[cur][(wc + i * 16 + ln) * 32 + quad * 8];
    }
    #pragma unroll
    for (int mb = 0; mb < 4; mb++)
      #pragma unroll
      for (int nb = 0; nb < 4; nb++)
        acc[mb][nb] = __builtin_amdgcn_mfma_f32_16x16x32_bf16(
            af[mb], bfr[nb], acc[mb][nb], 0, 0, 0);
    __syncthreads();
  }
#undef STG

  int colb = col0 + wc;
  int seg = colb >> 9;
  const float* bp = job ? (seg ? bv2 : bk2)
                        : (seg == 0 ? bq : seg == 1 ? bk : bv0);
  short* ob = job ? (out1 + (size_t)seg * ((size_t)MKV * D_MODEL))
                  : (out0 + (size_t)seg * ((size_t)MQ * D_MODEL));
  float bvv[4];
  #pragma unroll
  for (int nb = 0; nb < 4; nb++) bvv[nb] = bp[(colb + nb * 16 + ln) & 511];
  #pragma unroll
  for (int mb = 0; mb < 4; mb++)
    #pragma unroll
    for (int i = 0; i < 4; i++) {
      size_t r = (size_t)(row0 + wr + mb * 16 + quad * 4 + i);
      #pragma unroll
      for (int nb = 0; nb < 4; nb++) {
        int col = colb + nb * 16 + ln;
        ob[r * 512 + (col & 511)] = f2bs(acc[mb][nb][i] + bvv[nb]);
      }
    }
}

// ---- per-set online softmax step (exp2 domain, defer-max THR=8) ----
template<bool CAUSAL>
__device__ __forceinline__ void softmax_step(
    f32x4 st[4], float& m_q, float& l_q, f32x4 o_acc[4],
    int qrow, bool maybe_masked, int kbase, int quad, int lane,
    unsigned pu[4][2]) {
  float sv[4][4];
  float mt = -__builtin_inff();
  if (CAUSAL && maybe_masked) {
    #pragma unroll
    for (int nb = 0; nb < 4; nb++)
      #pragma unroll
      for (int i = 0; i < 4; i++) {
        float v = st[nb][i] * SCALE2;
        if ((kbase + nb * 16 + quad * 4 + i) > qrow) v = -__builtin_inff();
        sv[nb][i] = v;
        mt = fmaxf(mt, v);
      }
  } else {
    #pragma unroll
    for (int nb = 0; nb < 4; nb++)
      #pragma unroll
      for (int i = 0; i < 4; i++) {
        float v = st[nb][i] * SCALE2;
        sv[nb][i] = v;
        mt = fmaxf(mt, v);
      }
  }
  mt = fmaxf(mt, __shfl_xor(mt, 16));
  mt = fmaxf(mt, __shfl_xor(mt, 32));
  bool skip = __all(mt <= m_q + 8.0f) != 0;       // defer-max (T13)
  float mnew = skip ? m_q : fmaxf(m_q, mt);
  if (!skip) {
    float alpha = __builtin_amdgcn_exp2f(m_q - mnew);
    l_q *= alpha;
    #pragma unroll
    for (int i = 0; i < 4; i++) {
      float ai = __shfl(alpha, ((lane >> 4) << 2) + i);
      #pragma unroll
      for (int nb = 0; nb < 4; nb++) o_acc[nb][i] *= ai;
    }
  }
  m_q = mnew;
  float rs = 0.f;
  #pragma unroll
  for (int nb = 0; nb < 4; nb++) {
    float p0 = __builtin_amdgcn_exp2f(sv[nb][0] - mnew);
    float p1 = __builtin_amdgcn_exp2f(sv[nb][1] - mnew);
    float p2 = __builtin_amdgcn_exp2f(sv[nb][2] - mnew);
    float p3 = __builtin_amdgcn_exp2f(sv[nb][3] - mnew);
    rs += (p0 + p1) + (p2 + p3);
    asm("v_cvt_pk_bf16_f32 %0, %1, %2" : "=v"(pu[nb][0]) : "v"(p0), "v"(p1));
    asm("v_cvt_pk_bf16_f32 %0, %1, %2" : "=v"(pu[nb][1]) : "v"(p2), "v"(p3));
  }
  rs += __shfl_xor(rs, 16);
  rs += __shfl_xor(rs, 32);
  l_q += rs;
}

// =======================================================================
// MFMA flash attention v5: 4 waves x 32 Q-rows (2 sets of 16) = 128/block.
// Each kf/vf LDS fragment feeds BOTH sets -> per-CU LDS traffic ~0.55x of
// v4 for the same Q coverage (flash was LDS-BW-bound, MfmaUtil 4-8%).
// dbuf K/V LDS, 1 barrier/tile, exp2 softmax, cvt_pk, causal-skip, defer-max.
// =======================================================================
template<bool CAUSAL, bool SAVE_ML>
__global__ __launch_bounds__(256)
void flash_mfma(const short* __restrict__ Q, const short* __restrict__ K,
                const short* __restrict__ V, short* __restrict__ O,
                float* __restrict__ m_out, float* __restrict__ l_out,
                int LQ, int LK) {
  __shared__ short Ks[2][64 * KSTR];
  __shared__ short Vt[2][64 * KSTR];
  __shared__ short Ps[4 * 32 * KSTR];     // 4 waves x 32 rows
  int qt = CAUSAL ? ((int)gridDim.x - 1 - (int)blockIdx.x) : (int)blockIdx.x;
  int bh = blockIdx.y;
  int b = bh >> 3, h = bh & 7;
  int tid = threadIdx.x, lane = tid & 63, w = tid >> 6;   // w in 0..3
  int quad = lane >> 4, ln = lane & 15;

  const short* qp0 = Q + (size_t)(b * LQ + qt * 128 + w * 32 + ln) * D_MODEL + h * HEAD_DIM;
  const short* qp1 = qp0 + (size_t)16 * D_MODEL;
  bf16x8 qf0[2], qf1[2];
  qf0[0] = *(const bf16x8*)(qp0 + quad * 8);
  qf0[1] = *(const bf16x8*)(qp0 + 32 + quad * 8);
  qf1[0] = *(const bf16x8*)(qp1 + quad * 8);
  qf1[1] = *(const bf16x8*)(qp1 + 32 + quad * 8);

  int qrow0 = qt * 128 + w * 32 + ln;
  int qrow1 = qrow0 + 16;
  float m0 = -__builtin_inff(), l0 = 0.f;
  float m1 = -__builtin_inff(), l1 = 0.f;
  f32x4 oa0[4], oa1[4];
  #pragma unroll
  for (int nb = 0; nb < 4; nb++) {
    oa0[nb] = (f32x4){0.f, 0.f, 0.f, 0.f};
    oa1[nb] = (f32x4){0.f, 0.f, 0.f, 0.f};
  }

  const short* Kb = K + (size_t)(b * LK) * D_MODEL + h * HEAD_DIM;
  const short* Vb = V + (size_t)(b * LK) * D_MODEL + h * HEAD_DIM;
  int sr = tid >> 2, sc = (tid & 3) * 16;          // K staging: 256 thr x 32B
  int br4 = (tid >> 4) * 4, bc4 = (tid & 15) * 4;  // V transpose staging

  bf16x8 krA, krB;
  bf16x4 vr0, vr1, vr2, vr3;

#define LOADKV(KT) do { \
    const short* kg_ = Kb + (size_t)((KT) * 64 + sr) * D_MODEL + sc; \
    krA = *(const bf16x8*)kg_; krB = *(const bf16x8*)(kg_ + 8); \
    const short* vg_ = Vb + (size_t)((KT) * 64 + br4) * D_MODEL + bc4; \
    vr0 = *(const bf16x4*)(vg_); \
    vr1 = *(const bf16x4*)(vg_ + D_MODEL); \
    vr2 = *(const bf16x4*)(vg_ + 2 * D_MODEL); \
    vr3 = *(const bf16x4*)(vg_ + 3 * D_MODEL); } while (0)

#define STORKV(BUF) do { \
    *(bf16x8*)&Ks[BUF][sr * KSTR + sc] = krA; \
    *(bf16x8*)&Ks[BUF][sr * KSTR + sc + 8] = krB; \
    _Pragma("unroll") \
    for (int jj = 0; jj < 4; jj++) { \
      bf16x4 t_; \
      t_[0] = vr0[jj]; t_[1] = vr1[jj]; t_[2] = vr2[jj]; t_[3] = vr3[jj]; \
      *(bf16x4*)&Vt[BUF][(bc4 + jj) * KSTR + br4] = t_; } } while (0)

  int nkt = CAUSAL ? (2 * qt + 2) : (LK >> 6);
  LOADKV(0);
  STORKV(0);
  if (nkt > 1) LOADKV(1);
  __syncthreads();

  for (int kt = 0; kt < nkt; kt++) {
    int cur = kt & 1;
    if (kt + 1 < nkt) {
      STORKV(cur ^ 1);
      if (kt + 2 < nkt) LOADKV(kt + 2);
    }

    // --- S^T = K @ Q^T, both q-sets share each kf fragment ---
    f32x4 st0[4], st1[4];
    __builtin_amdgcn_s_setprio(1);
    #pragma unroll
    for (int nb = 0; nb < 4; nb++) {
      st0[nb] = (f32x4){0.f, 0.f, 0.f, 0.f};
      st1[nb] = (f32x4){0.f, 0.f, 0.f, 0.f};
      bf16x8 kf0 = *(const bf16x8*)&Ks[cur][(nb * 16 + ln) * KSTR + quad * 8];
      bf16x8 kf1 = *(const bf16x8*)&Ks[cur][(nb * 16 + ln) * KSTR + 32 + quad * 8];
      st0[nb] = __builtin_amdgcn_mfma_f32_16x16x32_bf16(kf0, qf0[0], st0[nb], 0, 0, 0);
      st1[nb] = __builtin_amdgcn_mfma_f32_16x16x32_bf16(kf0, qf1[0], st1[nb], 0, 0, 0);
      st0[nb] = __builtin_amdgcn_mfma_f32_16x16x32_bf16(kf1, qf0[1], st0[nb], 0, 0, 0);
      st1[nb] = __builtin_amdgcn_mfma_f32_16x16x32_bf16(kf1, qf1[1], st1[nb], 0, 0, 0);
    }
    __builtin_amdgcn_s_setprio(0);

    // --- softmax per set ---
    int kbase = kt * 64;
    unsigned pu0[4][2], pu1[4][2];
    bool mm0 = (kbase + 63) > (qt * 128 + w * 32);
    bool mm1 = (kbase + 63) > (qt * 128 + w * 32 + 16);
    softmax_step<CAUSAL>(st0, m0, l0, oa0, qrow0, mm0, kbase, quad, lane, pu0);
    softmax_step<CAUSAL>(st1, m1, l1, oa1, qrow1, mm1, kbase, quad, lane, pu1);

    // --- write P (per-wave region, rows: set*16 + ln) ---
    #pragma unroll
    for (int nb = 0; nb < 4; nb++) {
      union { unsigned u[2]; bf16x4 v; } a, bq;
      a.u[0] = pu0[nb][0]; a.u[1] = pu0[nb][1];
      bq.u[0] = pu1[nb][0]; bq.u[1] = pu1[nb][1];
      *(bf16x4*)&Ps[(w * 32 + ln) * KSTR + nb * 16 + quad * 4] = a.v;
      *(bf16x4*)&Ps[(w * 32 + 16 + ln) * KSTR + nb * 16 + quad * 4] = bq.v;
    }

    // --- O += P @ V, both sets share each vf fragment ---
    __builtin_amdgcn_s_setprio(1);
    #pragma unroll
    for (int kb = 0; kb < 2; kb++) {
      bf16x8 pf0 = *(const bf16x8*)&Ps[(w * 32 + ln) * KSTR + kb * 32 + quad * 8];
      bf16x8 pf1 = *(const bf16x8*)&Ps[(w * 32 + 16 + ln) * KSTR + kb * 32 + quad * 8];
      #pragma unroll
      for (int nb = 0; nb < 4; nb++) {
        bf16x8 vf = *(const bf16x8*)&Vt[cur][(nb * 16 + ln) * KSTR + kb * 32 + quad * 8];
        oa0[nb] = __builtin_amdgcn_mfma_f32_16x16x32_bf16(pf0, vf, oa0[nb], 0, 0, 0);
        oa1[nb] = __builtin_amdgcn_mfma_f32_16x16x32_bf16(pf1, vf, oa1[nb], 0, 0, 0);
      }
    }
    __builtin_amdgcn_s_setprio(0);
    __syncthreads();
  }
#undef LOADKV
#undef STORKV

  short* Ob0 = O + (size_t)(b * LQ + qt * 128 + w * 32 + quad * 4) * D_MODEL + h * HEAD_DIM;
  short* Ob1 = Ob0 + (size_t)16 * D_MODEL;
  #pragma unroll
  for (int i = 0; i < 4; i++) {
    float li0 = __shfl(l0, ((lane >> 4) << 2) + i);
    float li1 = __shfl(l1, ((lane >> 4) << 2) + i);
    float iv0 = 1.f / li0, iv1 = 1.f / li1;
    #pragma unroll
    for (int nb = 0; nb < 4; nb++) {
      Ob0[(size_t)i * D_MODEL + nb * 16 + ln] = f2bs(oa0[nb][i] * iv0);
      Ob1[(size_t)i * D_MODEL + nb * 16 + ln] = f2bs(oa1[nb][i] * iv1);
    }
  }
  if (SAVE_ML && lane < 16) {
    int r0 = bh * LQ + qt * 128 + w * 32 + lane;
    m_out[r0] = m0; l_out[r0] = l0;
    m_out[r0 + 16] = m1; l_out[r0 + 16] = l1;
  }
}

// ---- last-layer CA probabilities (bf16 Q/K, exp2-domain m/l) ----
__global__ __launch_bounds__(256)
void attn_prob_mfma(const short* __restrict__ Q, const short* __restrict__ K,
                    const float* __restrict__ m_in, const float* __restrict__ l_in,
                    float* __restrict__ out) {
  __shared__ short Ks[64 * KSTR];
  int qt = blockIdx.x, bh = blockIdx.y;
  int b = bh >> 3, h = bh & 7;
  int tid = threadIdx.x, lane = tid & 63, w = tid >> 6;
  int quad = lane >> 4, ln = lane & 15;
  const short* qp = Q + (size_t)(b * SEQ_C + qt * 64 + w * 16 + ln) * D_MODEL + h * HEAD_DIM;
  bf16x8 qf[2];
  qf[0] = *(const bf16x8*)(qp + quad * 8);
  qf[1] = *(const bf16x8*)(qp + 32 + quad * 8);
  float m_r[4], il[4];
  #pragma unroll
  for (int i = 0; i < 4; i++) {
    int r = bh * SEQ_C + qt * 64 + w * 16 + quad * 4 + i;
    m_r[i] = m_in[r]; il[i] = 1.f / l_in[r];
  }
  const short* Kb = K + (size_t)(b * SEQ_P) * D_MODEL + h * HEAD_DIM;
  int sr = tid >> 2, sc = (tid & 3) * 16;
  bf16x8 krA, krB;
  {
    const short* kg = Kb + (size_t)sr * D_MODEL + sc;
    krA = *(const bf16x8*)kg; krB = *(const bf16x8*)(kg + 8);
  }
  for (int kt = 0; kt < (SEQ_P >> 6); kt++) {
    __syncthreads();
    *(bf16x8*)&Ks[sr * KSTR + sc]     = krA;
    *(bf16x8*)&Ks[sr * KSTR + sc + 8] = krB;
    if (kt + 1 < (SEQ_P >> 6)) {
      const short* kg = Kb + (size_t)((kt + 1) * 64 + sr) * D_MODEL + sc;
      krA = *(const bf16x8*)kg; krB = *(const bf16x8*)(kg + 8);
    }
    __syncthreads();
    #pragma unroll
    for (int nb = 0; nb < 4; nb++) {
      f32x4 s = (f32x4){0.f, 0.f, 0.f, 0.f};
      bf16x8 kf0 = *(const bf16x8*)&Ks[(nb * 16 + ln) * KSTR + quad * 8];
      bf16x8 kf1 = *(const bf16x8*)&Ks[(nb * 16 + ln) * KSTR + 32 + quad * 8];
      s = __builtin_amdgcn_mfma_f32_16x16x32_bf16(qf[0], kf0, s, 0, 0, 0);
      s = __builtin_amdgcn_mfma_f32_16x16x32_bf16(qf[1], kf1, s, 0, 0, 0);
      #pragma unroll
      for (int i = 0; i < 4; i++) {
        size_t off = ((size_t)bh * SEQ_C + qt * 64 + w * 16 + quad * 4 + i) * SEQ_P
                   + kt * 64 + nb * 16 + ln;
        out[off] = __builtin_amdgcn_exp2f(s[i] * SCALE2 - m_r[i]) * il[i];
      }
    }
  }
}

// ---- fused residual add + layernorm, bf16 residual stream ----
// MODE 0: y is bf16. MODE 1: y,y2 are fp32 (FF2 split-K partials).
template<int MODE>
__global__ __launch_bounds__(256)
void add_ln_kernel(short* __restrict__ xb, const short* __restrict__ ybf,
                   const float* __restrict__ yf, const float* __restrict__ y2f,
                   const float* __restrict__ g, const float* __restrict__ b) {
  int row = blockIdx.x * 4 + (threadIdx.x >> 6);
  int lane = threadIdx.x & 63;
  int c0 = lane * 8;
  short* xr = xb + (size_t)row * D_MODEL;
  float v[8]; float s = 0.f, sq = 0.f;
  bf16x8 xv = *(const bf16x8*)(xr + c0);
  if (MODE == 0) {
    bf16x8 yv = *(const bf16x8*)(ybf + (size_t)row * D_MODEL + c0);
    #pragma unroll
    for (int i = 0; i < 8; i++) {
      float t = bs2f(xv[i]) + bs2f(yv[i]);
      v[i] = t; s += t; sq += t * t;
    }
  } else {
    const float* yr = yf + (size_t)row * D_MODEL + c0;
    const float* y2r = y2f + (size_t)row * D_MODEL + c0;
    float4 a0 = *(const float4*)(yr);
    float4 a1 = *(const float4*)(yr + 4);
    float4 c0v = *(const float4*)(y2r);
    float4 c1v = *(const float4*)(y2r + 4);
    float ya[8] = {a0.x + c0v.x, a0.y + c0v.y, a0.z + c0v.z, a0.w + c0v.w,
                   a1.x + c1v.x, a1.y + c1v.y, a1.z + c1v.z, a1.w + c1v.w};
    #pragma unroll
    for (int i = 0; i < 8; i++) {
      float t = bs2f(xv[i]) + ya[i];
      v[i] = t; s += t; sq += t * t;
    }
  }
  #pragma unroll
  for (int m = 1; m < 64; m <<= 1) { s += __shfl_xor(s, m); sq += __shfl_xor(sq, m); }
  float mu = s * (1.0f / 512.0f);
  float var = sq * (1.0f / 512.0f) - mu * mu;
  float rstd = rsqrtf(var + 1e-5f);
  float4 g0 = *(const float4*)(g + c0);
  float4 g1 = *(const float4*)(g + c0 + 4);
  float4 b0 = *(const float4*)(b + c0);
  float4 b1 = *(const float4*)(b + c0 + 4);
  float ga[8] = {g0.x, g0.y, g0.z, g0.w, g1.x, g1.y, g1.z, g1.w};
  float ba[8] = {b0.x, b0.y, b0.z, b0.w, b1.x, b1.y, b1.z, b1.w};
  bf16x8 o;
  #pragma unroll
  for (int i = 0; i < 8; i++)
    o[i] = f2bs((v[i] - mu) * rstd * ga[i] + ba[i]);
  *(bf16x8*)(xr + c0) = o;
}

extern "C" void kernel_launch(void* const* d_in, const int* in_sizes, int n_in,
                              void* d_out, int out_size, void* d_ws, size_t ws_size,
                              hipStream_t stream) {
  (void)in_sizes; (void)n_in; (void)out_size; (void)ws_size;
  const int*   cds      = (const int*)d_in[0];
  const float* enc_prot = (const float*)d_in[1];
  const float* tok_emb  = (const float*)d_in[4];
  const float* pos_emb  = (const float*)d_in[5];
  const float* sa_wq = (const float*)d_in[6];  const float* sa_bq = (const float*)d_in[7];
  const float* sa_wk = (const float*)d_in[8];  const float* sa_bk = (const float*)d_in[9];
  const float* sa_wv = (const float*)d_in[10]; const float* sa_bv = (const float*)d_in[11];
  const float* sa_wo = (const float*)d_in[12]; const float* sa_bo = (const float*)d_in[13];
  const float* ca_wq = (const float*)d_in[14]; const float* ca_bq = (const float*)d_in[15];
  const float* ca_wk = (const float*)d_in[16]; const float* ca_bk = (const float*)d_in[17];
  const float* ca_wv = (const float*)d_in[18]; const float* ca_bv = (const float*)d_in[19];
  const float* ca_wo = (const float*)d_in[20]; const float* ca_bo = (const float*)d_in[21];
  const float* ff_w1 = (const float*)d_in[22]; const float* ff_b1 = (const float*)d_in[23];
  const float* ff_w2 = (const float*)d_in[24]; const float* ff_b2 = (const float*)d_in[25];
  const float* ln1_g = (const float*)d_in[26]; const float* ln1_b = (const float*)d_in[27];
  const float* ln2_g = (const float*)d_in[28]; const float* ln2_b = (const float*)d_in[29];
  const float* ln3_g = (const float*)d_in[30]; const float* ln3_b = (const float*)d_in[31];
  const float* fcw   = (const float*)d_in[32]; const float* fcb   = (const float*)d_in[33];

  // ---- workspace layout (bf16 residual stream; no fp32 x mirror) ----
  float* y    = (float*)d_ws;                               // MQ*D f32 (FF2 partial z=0)
  float* mbuf = y + (size_t)MQ * D_MODEL;
  float* lbuf = mbuf + (size_t)BATCH * N_HEADS * SEQ_C;
  short* xb   = (short*)(lbuf + (size_t)BATCH * N_HEADS * SEQ_C); // residual (bf16)
  short* yb   = xb + (size_t)MQ * D_MODEL;                  // sublayer out (bf16)
  short* qb   = yb + (size_t)MQ * D_MODEL;
  short* kb   = qb + (size_t)MQ * D_MODEL;
  short* vb   = kb + (size_t)MQ * D_MODEL;
  short* ctxb = vb + (size_t)MQ * D_MODEL;
  short* hb   = qb;                                         // FFN hidden aliases qb..ctxb
  short* encb = ctxb + (size_t)MQ * D_MODEL;
  short* ckb  = encb + (size_t)MKV * D_MODEL;               // CA K (per-layer)
  short* cvb  = ckb + (size_t)MKV * D_MODEL;                // CA V (per-layer)
  short* wtb  = cvb + (size_t)MKV * D_MODEL;
  short* wts  = wtb + (size_t)128 * D_MODEL;
  const size_t WSZ = (size_t)NLAYER * D_MODEL * D_MODEL;
  short* w_saqkv = wts;
  short* w_sao   = w_saqkv + 3 * WSZ;
  short* w_caq   = w_sao + WSZ;
  short* w_cakv  = w_caq + WSZ;
  short* w_cao   = w_cakv + 2 * WSZ;
  short* w_ff1   = w_cao + WSZ;
  short* w_ff2   = w_ff1 + (size_t)NLAYER * D_MODEL * FFDIM;
  float* y2   = (float*)(w_ff2 + (size_t)NLAYER * D_MODEL * FFDIM); // dedicated 16MB

  float* logits = (float*)d_out;
  float* attn   = logits + (size_t)MQ * VOCAB;

  const size_t L1536 = (size_t)1536 * 512, L1024 = (size_t)1024 * 512, L512 = (size_t)512 * 512;

  // ---- prologue ----
  embed_kernel<<<MQ * D_MODEL / 1024, 256, 0, stream>>>(cds, tok_emb, pos_emb, xb);
  cvtf2b_kernel<<<(size_t)MKV * D_MODEL / 1024, 256, 0, stream>>>(enc_prot, encb);
  logits_wt_kernel<<<128 * D_MODEL / 256, 256, 0, stream>>>(fcw, wtb);
  {
    WtArgs a;
    a.src[0] = sa_wq; a.dst[0] = w_saqkv; a.ldz[0] = L1536; a.row_off[0] = 0;
    a.src[1] = sa_wk; a.dst[1] = w_saqkv; a.ldz[1] = L1536; a.row_off[1] = 512;
    a.src[2] = sa_wv; a.dst[2] = w_saqkv; a.ldz[2] = L1536; a.row_off[2] = 1024;
    a.src[3] = sa_wo; a.dst[3] = w_sao;   a.ldz[3] = L512;  a.row_off[3] = 0;
    a.src[4] = ca_wq; a.dst[4] = w_caq;   a.ldz[4] = L512;  a.row_off[4] = 0;
    a.src[5] = ca_wk; a.dst[5] = w_cakv;  a.ldz[5] = L1024; a.row_off[5] = 0;
    a.src[6] = ca_wv; a.dst[6] = w_cakv;  a.ldz[6] = L1024; a.row_off[6] = 512;
    a.src[7] = ca_wo; a.dst[7] = w_cao;   a.ldz[7] = L512;  a.row_off[7] = 0;
    wtrans8_kernel<<<dim3(16, 16, 8 * NLAYER), 256, 0, stream>>>(a);
  }
  wtrans_kernel<<<dim3(FFDIM / 32, D_MODEL / 32, NLAYER), 256, 0, stream>>>(
      ff_w1, w_ff1, D_MODEL, FFDIM, (size_t)FFDIM * 512);
  wtrans_kernel<<<dim3(D_MODEL / 32, FFDIM / 32, NLAYER), 256, 0, stream>>>(
      ff_w2, w_ff2, FFDIM, D_MODEL, (size_t)512 * FFDIM);

  dim3 gq64(MQ / 64, D_MODEL / 128);    // (128,4) MT=64
  dim3 gf1(MQ / 128, FFDIM / 128);      // (64,16) MT=128
  dim3 gff2(MQ / 128, D_MODEL / 128, 2);// (64,4,2) MT=128 split-K
  dim3 glg(MQ / 64, 1);                 // MT=64
  dim3 ga(SEQ_C / 128, BATCH * N_HEADS);    // flash: 128 Q-rows, 256 thr
  dim3 gap(SEQ_C / 64, BATCH * N_HEADS);

  for (int i = 0; i < NLAYER; i++) {
    size_t wo_ = (size_t)i * D_MODEL * D_MODEL, bo_ = (size_t)i * D_MODEL;
    size_t wf_ = (size_t)i * D_MODEL * FFDIM;
    // --- layer-start mega: SA QKV + CA KV ---
    gemm_mega<<<dim3(1024), 256, 0, stream>>>(
        xb, w_saqkv + (size_t)i * L1536, sa_bq + bo_, sa_bk + bo_, sa_bv + bo_, qb,
        encb, w_cakv + (size_t)i * L1024, ca_bk + bo_, ca_bv + bo_, ckb);
    flash_mfma<true,  false><<<ga, 256, 0, stream>>>(qb, kb, vb, ctxb, nullptr, nullptr, SEQ_C, SEQ_C);
    gemm_mfma<0,1,64><<<gq64, 256, 0, stream>>>(ctxb, w_sao + wo_,
        sa_bo + bo_, nullptr, nullptr, nullptr, nullptr, yb, 512, 512, 512, 0);
    add_ln_kernel<0><<<MQ / 4, 256, 0, stream>>>(xb, yb, nullptr, nullptr, ln1_g + bo_, ln1_b + bo_);
    // --- cross attention ---
    gemm_mfma<0,1,64><<<gq64, 256, 0, stream>>>(xb, w_caq + wo_,
        ca_bq + bo_, nullptr, nullptr, nullptr, nullptr, qb, 512, 512, 512, 0);
    if (i == NLAYER - 1) {
      flash_mfma<false, true><<<ga, 256, 0, stream>>>(qb, ckb, cvb, ctxb, mbuf, lbuf, SEQ_C, SEQ_P);
      attn_prob_mfma<<<gap, 256, 0, stream>>>(qb, ckb, mbuf, lbuf, attn);
    } else {
      flash_mfma<false, false><<<ga, 256, 0, stream>>>(qb, ckb, cvb, ctxb, nullptr, nullptr, SEQ_C, SEQ_P);
    }
    gemm_mfma<0,1,64><<<gq64, 256, 0, stream>>>(ctxb, w_cao + wo_,
        ca_bo + bo_, nullptr, nullptr, nullptr, nullptr, yb, 512, 512, 512, 0);
    add_ln_kernel<0><<<MQ / 4, 256, 0, stream>>>(xb, yb, nullptr, nullptr, ln2_g + bo_, ln2_b + bo_);
    // --- FFN (FF2 split-K2 -> y + y2, fp32 partials) ---
    gemm_mfma<1,1,128><<<gf1, 256, 0, stream>>>(xb, w_ff1 + wf_,
        ff_b1 + (size_t)i * FFDIM, nullptr, nullptr, nullptr, nullptr, hb, FFDIM, 512, FFDIM, 0);
    gemm_mfma<0,0,128,1><<<gff2, 256, 0, stream>>>(hb, w_ff2 + wf_,
        ff_b2 + bo_, nullptr, nullptr, y, y2, nullptr, 512, FFDIM, 512, 0);
    add_ln_kernel<1><<<MQ / 4, 256, 0, stream>>>(xb, nullptr, y, y2, ln3_g + bo_, ln3_b + bo_);
  }
  // --- logits via MFMA (padded N=128, write-guard 70) ---
  gemm_mfma<0,3,64><<<glg, 256, 0, stream>>>(xb, wtb,
      fcb, nullptr, nullptr, logits, nullptr, nullptr, 128, 512, VOCAB, 0);
}

// Round 10
// 1142.719 us; speedup vs baseline: 1.0277x; 1.0277x over previous
//
#include <hip/hip_runtime.h>

typedef __attribute__((ext_vector_type(8))) short bf16x8;
typedef __attribute__((ext_vector_type(4))) short bf16x4;
typedef __attribute__((ext_vector_type(2))) short bf16x2;
typedef __attribute__((ext_vector_type(4))) float f32x4;

#define D_MODEL 512
#define N_HEADS 8
#define HEAD_DIM 64
#define SEQ_C 1024
#define SEQ_P 512
#define BATCH 8
#define FFDIM 2048
#define VOCAB 70
#define NLAYER 4
#define MQ (BATCH*SEQ_C)    /* 8192 */
#define MKV (BATCH*SEQ_P)   /* 4096 */
#define KSTR 72             /* flash LDS row stride in bf16 units */
#define SCALE2 0.18033688011112043f   /* 0.125 * log2(e) */

__device__ __forceinline__ short f2bs(float f) {   // f32 -> bf16 bits, RNE
  union { float f; unsigned u; } v; v.f = f;
  unsigned r = (v.u + 0x7FFFu + ((v.u >> 16) & 1u)) >> 16;
  return (short)r;
}

__device__ __forceinline__ float bs2f(short s) {   // bf16 bits -> f32
  union { float f; unsigned u; } v;
  v.u = ((unsigned)(unsigned short)s) << 16;
  return v.f;
}

__device__ __forceinline__ void gl_lds16(const void* g, void* l) {
  __builtin_amdgcn_global_load_lds(
      (const __attribute__((address_space(1))) void*)g,
      (__attribute__((address_space(3))) void*)l, 16, 0, 0);
}

// ---------------- embedding: bf16 residual stream only ----------------
__global__ __launch_bounds__(256)
void embed_kernel(const int* __restrict__ cds, const float* __restrict__ tok,
                  const float* __restrict__ pos, short* __restrict__ xb) {
  int idx = (blockIdx.x * 256 + threadIdx.x) * 4;
  int row = idx >> 9, c = idx & 511;
  int l = row & (SEQ_C - 1);
  int t = cds[row];
  float4 tv = *(const float4*)(tok + (size_t)t * D_MODEL + c);
  float4 pv = *(const float4*)(pos + (size_t)l * D_MODEL + c);
  bf16x4 o;
  o[0] = f2bs(tv.x * 22.627416997969522f + pv.x);
  o[1] = f2bs(tv.y * 22.627416997969522f + pv.y);
  o[2] = f2bs(tv.z * 22.627416997969522f + pv.z);
  o[3] = f2bs(tv.w * 22.627416997969522f + pv.w);
  *(bf16x4*)(xb + idx) = o;
}

// fp32 -> bf16 bulk convert (enc_prot)
__global__ __launch_bounds__(256)
void cvtf2b_kernel(const float* __restrict__ in, short* __restrict__ out) {
  int i = (blockIdx.x * 256 + threadIdx.x) * 4;
  float4 v = *(const float4*)(in + i);
  bf16x4 o;
  o[0] = f2bs(v.x); o[1] = f2bs(v.y); o[2] = f2bs(v.z); o[3] = f2bs(v.w);
  *(bf16x4*)(out + i) = o;
}

// ---- merged 8-way square (512x512) weight transpose, grid z = 8*NLAYER ----
struct WtArgs {
  const float* src[8];
  short* dst[8];
  size_t ldz[8];
  int row_off[8];
};

__global__ __launch_bounds__(256)
void wtrans8_kernel(WtArgs a) {
  __shared__ float T[32][33];
  int z = blockIdx.z;
  int job = z >> 2, layer = z & 3;
  const float* W = a.src[job] + (size_t)layer * D_MODEL * D_MODEL;
  short* Wt = a.dst[job] + (size_t)layer * a.ldz[job];
  int row_off = a.row_off[job];
  int n0 = blockIdx.x * 32, k0 = blockIdx.y * 32;
  int r = threadIdx.x >> 3, c4 = (threadIdx.x & 7) * 4;
  float4 v = *(const float4*)(W + (size_t)(k0 + r) * D_MODEL + n0 + c4);
  T[c4 + 0][r] = v.x; T[c4 + 1][r] = v.y; T[c4 + 2][r] = v.z; T[c4 + 3][r] = v.w;
  __syncthreads();
  bf16x4 o;
  o[0] = f2bs(T[r][c4 + 0]); o[1] = f2bs(T[r][c4 + 1]);
  o[2] = f2bs(T[r][c4 + 2]); o[3] = f2bs(T[r][c4 + 3]);
  *(bf16x4*)&Wt[(size_t)(row_off + n0 + r) * D_MODEL + k0 + c4] = o;
}

// W [K,N] fp32 -> Wt [N,K] bf16, per-layer via blockIdx.z (FFN weights)
__global__ __launch_bounds__(256)
void wtrans_kernel(const float* __restrict__ W, short* __restrict__ Wt,
                   int K, int N, size_t dst_ldz) {
  __shared__ float T[32][33];
  size_t lo_s = (size_t)blockIdx.z * K * N;
  size_t lo_d = (size_t)blockIdx.z * dst_ldz;
  int n0 = blockIdx.x * 32, k0 = blockIdx.y * 32;
  int r = threadIdx.x >> 3, c4 = (threadIdx.x & 7) * 4;
  float4 v = *(const float4*)(W + lo_s + (size_t)(k0 + r) * N + n0 + c4);
  T[c4 + 0][r] = v.x; T[c4 + 1][r] = v.y; T[c4 + 2][r] = v.z; T[c4 + 3][r] = v.w;
  __syncthreads();
  bf16x4 o;
  o[0] = f2bs(T[r][c4 + 0]); o[1] = f2bs(T[r][c4 + 1]);
  o[2] = f2bs(T[r][c4 + 2]); o[3] = f2bs(T[r][c4 + 3]);
  *(bf16x4*)&Wt[lo_d + (size_t)(n0 + r) * K + k0 + c4] = o;
}

// fc_out_w [512,70] -> padded bf16 [128][512] (rows >= 70 zero)
__global__ __launch_bounds__(256)
void logits_wt_kernel(const float* __restrict__ w, short* __restrict__ wt) {
  int idx = blockIdx.x * 256 + threadIdx.x;
  int r = idx >> 9, c = idx & 511;
  wt[idx] = (r < VOCAB) ? f2bs(w[c * VOCAB + r]) : (short)0;
}

// =======================================================================
// bf16 MFMA GEMM, MT x 128 tile, BK=32, 4 waves, 2-phase double-buffered.
// OMODE: 0 fp32 out; 1 bf16 out; 2 bf16 segment-split; 3 fp32 guarded.
// KSPLIT: blockIdx.z halves K; z=0 -> Cf (+bias), z=1 -> Cf2 (no bias).
// =======================================================================
template<int ACT, int OMODE, int MT, int KSPLIT = 0>
__global__ __launch_bounds__(256)
void gemm_mfma(const short* __restrict__ Ab, const short* __restrict__ Wt,
               const float* __restrict__ b0, const float* __restrict__ b1,
               const float* __restrict__ b2,
               float* __restrict__ Cf, float* __restrict__ Cf2,
               short* __restrict__ Cb,
               int N, int K, int ldc, size_t segstride) {
  constexpr int MREP = MT / 32;
  __shared__ __align__(16) short As[2][MT * 32];
  __shared__ __align__(16) short Bs[2][4096];
  int tid = threadIdx.x, lane = tid & 63, w = tid >> 6;
  int quad = lane >> 4, ln = lane & 15;
  int row0 = blockIdx.x * MT, col0 = blockIdx.y * 128;
  int kz = KSPLIT ? (int)blockIdx.z : 0;
  int Keff = KSPLIT ? (K >> 1) : K;
  int koff = kz * Keff;
  int q0 = tid, q1 = tid + 256;
  const short* a0 = Ab + (size_t)(row0 + (q0 >> 2)) * K + koff + (q0 & 3) * 8;
  const short* a1 = Ab + (size_t)(row0 + (q1 >> 2)) * K + koff + (q1 & 3) * 8;
  const short* w0 = Wt + (size_t)(col0 + (q0 >> 2)) * K + koff + (q0 & 3) * 8;
  const short* w1 = Wt + (size_t)(col0 + (q1 >> 2)) * K + koff + (q1 & 3) * 8;
  int wr = (w >> 1) * (MT / 2), wc = (w & 1) * 64;
  f32x4 acc[MREP][4];
  #pragma unroll
  for (int mb = 0; mb < MREP; mb++)
    #pragma unroll
    for (int nb = 0; nb < 4; nb++) acc[mb][nb] = (f32x4){0.f, 0.f, 0.f, 0.f};

  int nt = Keff >> 5;
#define STG(ko, buf) do { \
    gl_lds16(a0 + (ko), &As[buf][w * 512]); \
    if (MT == 128) gl_lds16(a1 + (ko), &As[buf][MT * 16 + w * 512]); \
    gl_lds16(w0 + (ko), &Bs[buf][w * 512]); \
    gl_lds16(w1 + (ko), &Bs[buf][2048 + w * 512]); } while (0)

  STG(0, 0);
  __syncthreads();
  for (int t = 0; t < nt; t++) {
    int cur = t & 1;
    if (t + 1 < nt) STG((t + 1) << 5, cur ^ 1);
    bf16x8 af[MREP], bfr[4];
    #pragma unroll
    for (int i = 0; i < MREP; i++)
      af[i] = *(const bf16x8*)&As[cur][(wr + i * 16 + ln) * 32 + quad * 8];
    #pragma unroll
    for (int i = 0; i < 4; i++)
      bfr[i] = *(const bf16x8*)&Bs[cur][(wc + i * 16 + ln) * 32 + quad * 8];
    #pragma unroll
    for (int mb = 0; mb < MREP; mb++)
      #pragma unroll
      for (int nb = 0; nb < 4; nb++)
        acc[mb][nb] = __builtin_amdgcn_mfma_f32_16x16x32_bf16(
            af[mb], bfr[nb], acc[mb][nb], 0, 0, 0);
    __syncthreads();
  }
#undef STG

  int colb = col0 + wc;
  const float* bp = b0;
  if (OMODE == 2) {
    int seg = colb >> 9;
    bp = (seg == 0) ? b0 : (seg == 1) ? b1 : b2;
  }
  float bv[4];
  #pragma unroll
  for (int nb = 0; nb < 4; nb++) {
    int col = colb + nb * 16 + ln;
    if (KSPLIT && kz)    bv[nb] = 0.f;
    else if (OMODE == 3) bv[nb] = (col < ldc) ? bp[col] : 0.f;
    else if (OMODE == 2) bv[nb] = bp[col & 511];
    else                 bv[nb] = bp[col];
  }
  float* Co = (KSPLIT && kz) ? Cf2 : Cf;
  size_t segoff = (OMODE == 2) ? (size_t)(colb >> 9) * segstride : 0;
  #pragma unroll
  for (int mb = 0; mb < MREP; mb++)
    #pragma unroll
    for (int i = 0; i < 4; i++) {
      size_t r = (size_t)(row0 + wr + mb * 16 + quad * 4 + i);
      #pragma unroll
      for (int nb = 0; nb < 4; nb++) {
        int col = colb + nb * 16 + ln;
        float v = acc[mb][nb][i] + bv[nb];
        if (ACT) v = fmaxf(v, 0.f);
        if (OMODE == 0)      Co[r * ldc + col] = v;
        else if (OMODE == 1) Cb[r * ldc + col] = f2bs(v);
        else if (OMODE == 2) Cb[segoff + r * 512 + (col & 511)] = f2bs(v);
        else if (col < ldc)  Co[r * ldc + col] = v;
      }
    }
}

// =======================================================================
// Mega launch: SA-QKV (768 blocks) + CA-KV (256 blocks), both MT=128, K=512.
// =======================================================================
__global__ __launch_bounds__(256)
void gemm_mega(const short* __restrict__ A0, const short* __restrict__ W0,
               const float* __restrict__ bq, const float* __restrict__ bk,
               const float* __restrict__ bv0, short* __restrict__ out0,
               const short* __restrict__ A1, const short* __restrict__ W1,
               const float* __restrict__ bk2, const float* __restrict__ bv2,
               short* __restrict__ out1) {
  __shared__ __align__(16) short As[2][4096];
  __shared__ __align__(16) short Bs[2][4096];
  const int K = 512;
  int bid = blockIdx.x;
  int job = bid >= 768;
  const short* Ab; const short* Wt; int row0, col0;
  if (!job) { Ab = A0; Wt = W0; row0 = (bid & 63) << 7; col0 = (bid >> 6) << 7; }
  else { int b2 = bid - 768; Ab = A1; Wt = W1; row0 = (b2 & 31) << 7; col0 = (b2 >> 5) << 7; }
  int tid = threadIdx.x, lane = tid & 63, w = tid >> 6;
  int quad = lane >> 4, ln = lane & 15;
  int q0 = tid, q1 = tid + 256;
  const short* a0 = Ab + (size_t)(row0 + (q0 >> 2)) * K + (q0 & 3) * 8;
  const short* a1 = Ab + (size_t)(row0 + (q1 >> 2)) * K + (q1 & 3) * 8;
  const short* w0 = Wt + (size_t)(col0 + (q0 >> 2)) * K + (q0 & 3) * 8;
  const short* w1 = Wt + (size_t)(col0 + (q1 >> 2)) * K + (q1 & 3) * 8;
  int wr = (w >> 1) * 64, wc = (w & 1) * 64;
  f32x4 acc[4][4];
  #pragma unroll
  for (int mb = 0; mb < 4; mb++)
    #pragma unroll
    for (int nb = 0; nb < 4; nb++) acc[mb][nb] = (f32x4){0.f, 0.f, 0.f, 0.f};

#define STG(ko, buf) do { \
    gl_lds16(a0 + (ko), &As[buf][w * 512]); \
    gl_lds16(a1 + (ko), &As[buf][2048 + w * 512]); \
    gl_lds16(w0 + (ko), &Bs[buf][w * 512]); \
    gl_lds16(w1 + (ko), &Bs[buf][2048 + w * 512]); } while (0)

  STG(0, 0);
  __syncthreads();
  for (int t = 0; t < 16; t++) {
    int cur = t & 1;
    if (t + 1 < 16) STG((t + 1) << 5, cur ^ 1);
    bf16x8 af[4], bfr[4];
    #pragma unroll
    for (int i = 0; i < 4; i++) {
      af[i]  = *(const bf16x8*)&As[cur][(wr + i * 16 + ln) * 32 + quad * 8];
      bfr[i] = *(const bf16x8*)&Bs[cur][(wc + i * 16 + ln) * 32 + quad * 8];
    }
    #pragma unroll
    for (int mb = 0; mb < 4; mb++)
      #pragma unroll
      for (int nb = 0; nb < 4; nb++)
        acc[mb][nb] = __builtin_amdgcn_mfma_f32_16x16x32_bf16(
            af[mb], bfr[nb], acc[mb][nb], 0, 0, 0);
    __syncthreads();
  }
#undef STG

  int colb = col0 + wc;
  int seg = colb >> 9;
  const float* bp = job ? (seg ? bv2 : bk2)
                        : (seg == 0 ? bq : seg == 1 ? bk : bv0);
  short* ob = job ? (out1 + (size_t)seg * ((size_t)MKV * D_MODEL))
                  : (out0 + (size_t)seg * ((size_t)MQ * D_MODEL));
  float bvv[4];
  #pragma unroll
  for (int nb = 0; nb < 4; nb++) bvv[nb] = bp[(colb + nb * 16 + ln) & 511];
  #pragma unroll
  for (int mb = 0; mb < 4; mb++)
    #pragma unroll
    for (int i = 0; i < 4; i++) {
      size_t r = (size_t)(row0 + wr + mb * 16 + quad * 4 + i);
      #pragma unroll
      for (int nb = 0; nb < 4; nb++) {
        int col = colb + nb * 16 + ln;
        ob[r * 512 + (col & 511)] = f2bs(acc[mb][nb][i] + bvv[nb]);
      }
    }
}

// =======================================================================
// MFMA flash attention v4 (REVERT from v5 — post-mortem r9): 8 waves /
// 128 Q-rows, dbuf K/V LDS, 1 barrier/tile, exp2 softmax, cvt_pk P-pack,
// causal-skip, defer-max (THR=8). v5's shared-fragment variant halved LDS
// traffic but also halved waves/CU (16->8) and doubled the serial softmax
// chain -> net regression; flash is latency-bound, not LDS-BW-bound.
// =======================================================================
template<bool CAUSAL, bool SAVE_ML>
__global__ __launch_bounds__(512)
void flash_mfma(const short* __restrict__ Q, const short* __restrict__ K,
                const short* __restrict__ V, short* __restrict__ O,
                float* __restrict__ m_out, float* __restrict__ l_out,
                int LQ, int LK) {
  __shared__ short Ks[2][64 * KSTR];
  __shared__ short Vt[2][64 * KSTR];
  __shared__ short Ps[8 * 16 * KSTR];
  int qt = CAUSAL ? ((int)gridDim.x - 1 - (int)blockIdx.x) : (int)blockIdx.x;
  int bh = blockIdx.y;
  int b = bh >> 3, h = bh & 7;
  int tid = threadIdx.x, lane = tid & 63, w = tid >> 6;
  int quad = lane >> 4, ln = lane & 15;

  const short* qp = Q + (size_t)(b * LQ + qt * 128 + w * 16 + ln) * D_MODEL + h * HEAD_DIM;
  bf16x8 qf[2];
  qf[0] = *(const bf16x8*)(qp + quad * 8);
  qf[1] = *(const bf16x8*)(qp + 32 + quad * 8);

  int qrow = qt * 128 + w * 16 + ln;
  float m_q = -__builtin_inff(), l_q = 0.f;
  f32x4 o_acc[4];
  #pragma unroll
  for (int nb = 0; nb < 4; nb++) o_acc[nb] = (f32x4){0.f, 0.f, 0.f, 0.f};

  const short* Kb = K + (size_t)(b * LK) * D_MODEL + h * HEAD_DIM;
  const short* Vb = V + (size_t)(b * LK) * D_MODEL + h * HEAD_DIM;
  int sr = tid >> 3, sc = (tid & 7) * 8;
  int br4 = (tid >> 4) * 4, bc4 = (tid & 15) * 4;
  bool vst = tid < 256;

  bf16x8 kr;
  bf16x4 vr0, vr1, vr2, vr3;

#define LOADKV(KT) do { \
    kr = *(const bf16x8*)(Kb + (size_t)((KT) * 64 + sr) * D_MODEL + sc); \
    if (vst) { \
      const short* vg_ = Vb + (size_t)((KT) * 64 + br4) * D_MODEL + bc4; \
      vr0 = *(const bf16x4*)(vg_); \
      vr1 = *(const bf16x4*)(vg_ + D_MODEL); \
      vr2 = *(const bf16x4*)(vg_ + 2 * D_MODEL); \
      vr3 = *(const bf16x4*)(vg_ + 3 * D_MODEL); } } while (0)

#define STORKV(BUF) do { \
    *(bf16x8*)&Ks[BUF][sr * KSTR + sc] = kr; \
    if (vst) { \
      _Pragma("unroll") \
      for (int jj = 0; jj < 4; jj++) { \
        bf16x4 t_; \
        t_[0] = vr0[jj]; t_[1] = vr1[jj]; t_[2] = vr2[jj]; t_[3] = vr3[jj]; \
        *(bf16x4*)&Vt[BUF][(bc4 + jj) * KSTR + br4] = t_; } } } while (0)

  int nkt = CAUSAL ? (2 * qt + 2) : (LK >> 6);
  LOADKV(0);
  STORKV(0);
  if (nkt > 1) LOADKV(1);
  __syncthreads();

  for (int kt = 0; kt < nkt; kt++) {
    int cur = kt & 1;
    if (kt + 1 < nkt) {
      STORKV(cur ^ 1);
      if (kt + 2 < nkt) LOADKV(kt + 2);
    }

    // --- S^T = K @ Q^T ---
    f32x4 st[4];
    __builtin_amdgcn_s_setprio(1);
    #pragma unroll
    for (int nb = 0; nb < 4; nb++) {
      st[nb] = (f32x4){0.f, 0.f, 0.f, 0.f};
      bf16x8 kf0 = *(const bf16x8*)&Ks[cur][(nb * 16 + ln) * KSTR + quad * 8];
      bf16x8 kf1 = *(const bf16x8*)&Ks[cur][(nb * 16 + ln) * KSTR + 32 + quad * 8];
      st[nb] = __builtin_amdgcn_mfma_f32_16x16x32_bf16(kf0, qf[0], st[nb], 0, 0, 0);
      st[nb] = __builtin_amdgcn_mfma_f32_16x16x32_bf16(kf1, qf[1], st[nb], 0, 0, 0);
    }
    __builtin_amdgcn_s_setprio(0);

    // --- softmax (exp2 domain), per lane q = ln ---
    float sv[4][4];
    float mt = -__builtin_inff();
    if (CAUSAL && (kt * 64 + 63 > qt * 128 + w * 16)) {
      #pragma unroll
      for (int nb = 0; nb < 4; nb++)
        #pragma unroll
        for (int i = 0; i < 4; i++) {
          float v = st[nb][i] * SCALE2;
          if ((kt * 64 + nb * 16 + quad * 4 + i) > qrow) v = -__builtin_inff();
          sv[nb][i] = v;
          mt = fmaxf(mt, v);
        }
    } else {
      #pragma unroll
      for (int nb = 0; nb < 4; nb++)
        #pragma unroll
        for (int i = 0; i < 4; i++) {
          float v = st[nb][i] * SCALE2;
          sv[nb][i] = v;
          mt = fmaxf(mt, v);
        }
    }
    mt = fmaxf(mt, __shfl_xor(mt, 16));
    mt = fmaxf(mt, __shfl_xor(mt, 32));
    bool skip = __all(mt <= m_q + 8.0f) != 0;       // defer-max (T13)
    float mnew = skip ? m_q : fmaxf(m_q, mt);
    if (!skip) {
      float alpha = __builtin_amdgcn_exp2f(m_q - mnew);
      l_q *= alpha;
      #pragma unroll
      for (int i = 0; i < 4; i++) {
        float ai = __shfl(alpha, ((lane >> 4) << 2) + i);
        #pragma unroll
        for (int nb = 0; nb < 4; nb++) o_acc[nb][i] *= ai;
      }
    }
    m_q = mnew;

    float rs = 0.f;
    unsigned pu[4][2];
    #pragma unroll
    for (int nb = 0; nb < 4; nb++) {
      float p0 = __builtin_amdgcn_exp2f(sv[nb][0] - mnew);
      float p1 = __builtin_amdgcn_exp2f(sv[nb][1] - mnew);
      float p2 = __builtin_amdgcn_exp2f(sv[nb][2] - mnew);
      float p3 = __builtin_amdgcn_exp2f(sv[nb][3] - mnew);
      rs += (p0 + p1) + (p2 + p3);
      asm("v_cvt_pk_bf16_f32 %0, %1, %2" : "=v"(pu[nb][0]) : "v"(p0), "v"(p1));
      asm("v_cvt_pk_bf16_f32 %0, %1, %2" : "=v"(pu[nb][1]) : "v"(p2), "v"(p3));
    }
    rs += __shfl_xor(rs, 16);
    rs += __shfl_xor(rs, 32);
    l_q += rs;

    // --- write P (layout [q=ln][kv]) ---
    #pragma unroll
    for (int nb = 0; nb < 4; nb++) {
      union { unsigned u[2]; bf16x4 v; } uu;
      uu.u[0] = pu[nb][0]; uu.u[1] = pu[nb][1];
      *(bf16x4*)&Ps[w * 16 * KSTR + ln * KSTR + nb * 16 + quad * 4] = uu.v;
    }

    // --- O += P @ V ---
    __builtin_amdgcn_s_setprio(1);
    #pragma unroll
    for (int kb = 0; kb < 2; kb++) {
      bf16x8 pf = *(const bf16x8*)&Ps[w * 16 * KSTR + ln * KSTR + kb * 32 + quad * 8];
      #pragma unroll
      for (int nb = 0; nb < 4; nb++) {
        bf16x8 vf = *(const bf16x8*)&Vt[cur][(nb * 16 + ln) * KSTR + kb * 32 + quad * 8];
        o_acc[nb] = __builtin_amdgcn_mfma_f32_16x16x32_bf16(pf, vf, o_acc[nb], 0, 0, 0);
      }
    }
    __builtin_amdgcn_s_setprio(0);
    __syncthreads();
  }
#undef LOADKV
#undef STORKV

  short* Ob = O + (size_t)(b * LQ + qt * 128 + w * 16 + quad * 4) * D_MODEL + h * HEAD_DIM;
  #pragma unroll
  for (int i = 0; i < 4; i++) {
    float li = __shfl(l_q, ((lane >> 4) << 2) + i);
    float inv = 1.f / li;
    #pragma unroll
    for (int nb = 0; nb < 4; nb++)
      Ob[(size_t)i * D_MODEL + nb * 16 + ln] = f2bs(o_acc[nb][i] * inv);
  }
  if (SAVE_ML && lane < 16) {
    int r = bh * LQ + qt * 128 + w * 16 + lane;
    m_out[r] = m_q;
    l_out[r] = l_q;
  }
}

// ---- last-layer CA probabilities (bf16 Q/K, exp2-domain m/l) ----
__global__ __launch_bounds__(256)
void attn_prob_mfma(const short* __restrict__ Q, const short* __restrict__ K,
                    const float* __restrict__ m_in, const float* __restrict__ l_in,
                    float* __restrict__ out) {
  __shared__ short Ks[64 * KSTR];
  int qt = blockIdx.x, bh = blockIdx.y;
  int b = bh >> 3, h = bh & 7;
  int tid = threadIdx.x, lane = tid & 63, w = tid >> 6;
  int quad = lane >> 4, ln = lane & 15;
  const short* qp = Q + (size_t)(b * SEQ_C + qt * 64 + w * 16 + ln) * D_MODEL + h * HEAD_DIM;
  bf16x8 qf[2];
  qf[0] = *(const bf16x8*)(qp + quad * 8);
  qf[1] = *(const bf16x8*)(qp + 32 + quad * 8);
  float m_r[4], il[4];
  #pragma unroll
  for (int i = 0; i < 4; i++) {
    int r = bh * SEQ_C + qt * 64 + w * 16 + quad * 4 + i;
    m_r[i] = m_in[r]; il[i] = 1.f / l_in[r];
  }
  const short* Kb = K + (size_t)(b * SEQ_P) * D_MODEL + h * HEAD_DIM;
  int sr = tid >> 2, sc = (tid & 3) * 16;
  bf16x8 krA, krB;
  {
    const short* kg = Kb + (size_t)sr * D_MODEL + sc;
    krA = *(const bf16x8*)kg; krB = *(const bf16x8*)(kg + 8);
  }
  for (int kt = 0; kt < (SEQ_P >> 6); kt++) {
    __syncthreads();
    *(bf16x8*)&Ks[sr * KSTR + sc]     = krA;
    *(bf16x8*)&Ks[sr * KSTR + sc + 8] = krB;
    if (kt + 1 < (SEQ_P >> 6)) {
      const short* kg = Kb + (size_t)((kt + 1) * 64 + sr) * D_MODEL + sc;
      krA = *(const bf16x8*)kg; krB = *(const bf16x8*)(kg + 8);
    }
    __syncthreads();
    #pragma unroll
    for (int nb = 0; nb < 4; nb++) {
      f32x4 s = (f32x4){0.f, 0.f, 0.f, 0.f};
      bf16x8 kf0 = *(const bf16x8*)&Ks[(nb * 16 + ln) * KSTR + quad * 8];
      bf16x8 kf1 = *(const bf16x8*)&Ks[(nb * 16 + ln) * KSTR + 32 + quad * 8];
      s = __builtin_amdgcn_mfma_f32_16x16x32_bf16(qf[0], kf0, s, 0, 0, 0);
      s = __builtin_amdgcn_mfma_f32_16x16x32_bf16(qf[1], kf1, s, 0, 0, 0);
      #pragma unroll
      for (int i = 0; i < 4; i++) {
        size_t off = ((size_t)bh * SEQ_C + qt * 64 + w * 16 + quad * 4 + i) * SEQ_P
                   + kt * 64 + nb * 16 + ln;
        out[off] = __builtin_amdgcn_exp2f(s[i] * SCALE2 - m_r[i]) * il[i];
      }
    }
  }
}

// ---- fused residual add + layernorm, bf16 residual stream ----
// MODE 0: y is bf16. MODE 1: y,y2 are fp32 (FF2 split-K partials).
template<int MODE>
__global__ __launch_bounds__(256)
void add_ln_kernel(short* __restrict__ xb, const short* __restrict__ ybf,
                   const float* __restrict__ yf, const float* __restrict__ y2f,
                   const float* __restrict__ g, const float* __restrict__ b) {
  int row = blockIdx.x * 4 + (threadIdx.x >> 6);
  int lane = threadIdx.x & 63;
  int c0 = lane * 8;
  short* xr = xb + (size_t)row * D_MODEL;
  float v[8]; float s = 0.f, sq = 0.f;
  bf16x8 xv = *(const bf16x8*)(xr + c0);
  if (MODE == 0) {
    bf16x8 yv = *(const bf16x8*)(ybf + (size_t)row * D_MODEL + c0);
    #pragma unroll
    for (int i = 0; i < 8; i++) {
      float t = bs2f(xv[i]) + bs2f(yv[i]);
      v[i] = t; s += t; sq += t * t;
    }
  } else {
    const float* yr = yf + (size_t)row * D_MODEL + c0;
    const float* y2r = y2f + (size_t)row * D_MODEL + c0;
    float4 a0 = *(const float4*)(yr);
    float4 a1 = *(const float4*)(yr + 4);
    float4 c0v = *(const float4*)(y2r);
    float4 c1v = *(const float4*)(y2r + 4);
    float ya[8] = {a0.x + c0v.x, a0.y + c0v.y, a0.z + c0v.z, a0.w + c0v.w,
                   a1.x + c1v.x, a1.y + c1v.y, a1.z + c1v.z, a1.w + c1v.w};
    #pragma unroll
    for (int i = 0; i < 8; i++) {
      float t = bs2f(xv[i]) + ya[i];
      v[i] = t; s += t; sq += t * t;
    }
  }
  #pragma unroll
  for (int m = 1; m < 64; m <<= 1) { s += __shfl_xor(s, m); sq += __shfl_xor(sq, m); }
  float mu = s * (1.0f / 512.0f);
  float var = sq * (1.0f / 512.0f) - mu * mu;
  float rstd = rsqrtf(var + 1e-5f);
  float4 g0 = *(const float4*)(g + c0);
  float4 g1 = *(const float4*)(g + c0 + 4);
  float4 b0 = *(const float4*)(b + c0);
  float4 b1 = *(const float4*)(b + c0 + 4);
  float ga[8] = {g0.x, g0.y, g0.z, g0.w, g1.x, g1.y, g1.z, g1.w};
  float ba[8] = {b0.x, b0.y, b0.z, b0.w, b1.x, b1.y, b1.z, b1.w};
  bf16x8 o;
  #pragma unroll
  for (int i = 0; i < 8; i++)
    o[i] = f2bs((v[i] - mu) * rstd * ga[i] + ba[i]);
  *(bf16x8*)(xr + c0) = o;
}

extern "C" void kernel_launch(void* const* d_in, const int* in_sizes, int n_in,
                              void* d_out, int out_size, void* d_ws, size_t ws_size,
                              hipStream_t stream) {
  (void)in_sizes; (void)n_in; (void)out_size; (void)ws_size;
  const int*   cds      = (const int*)d_in[0];
  const float* enc_prot = (const float*)d_in[1];
  const float* tok_emb  = (const float*)d_in[4];
  const float* pos_emb  = (const float*)d_in[5];
  const float* sa_wq = (const float*)d_in[6];  const float* sa_bq = (const float*)d_in[7];
  const float* sa_wk = (const float*)d_in[8];  const float* sa_bk = (const float*)d_in[9];
  const float* sa_wv = (const float*)d_in[10]; const float* sa_bv = (const float*)d_in[11];
  const float* sa_wo = (const float*)d_in[12]; const float* sa_bo = (const float*)d_in[13];
  const float* ca_wq = (const float*)d_in[14]; const float* ca_bq = (const float*)d_in[15];
  const float* ca_wk = (const float*)d_in[16]; const float* ca_bk = (const float*)d_in[17];
  const float* ca_wv = (const float*)d_in[18]; const float* ca_bv = (const float*)d_in[19];
  const float* ca_wo = (const float*)d_in[20]; const float* ca_bo = (const float*)d_in[21];
  const float* ff_w1 = (const float*)d_in[22]; const float* ff_b1 = (const float*)d_in[23];
  const float* ff_w2 = (const float*)d_in[24]; const float* ff_b2 = (const float*)d_in[25];
  const float* ln1_g = (const float*)d_in[26]; const float* ln1_b = (const float*)d_in[27];
  const float* ln2_g = (const float*)d_in[28]; const float* ln2_b = (const float*)d_in[29];
  const float* ln3_g = (const float*)d_in[30]; const float* ln3_b = (const float*)d_in[31];
  const float* fcw   = (const float*)d_in[32]; const float* fcb   = (const float*)d_in[33];

  // ---- workspace layout (bf16 residual stream; no fp32 x mirror) ----
  float* y    = (float*)d_ws;                               // MQ*D f32 (FF2 partial z=0)
  float* mbuf = y + (size_t)MQ * D_MODEL;
  float* lbuf = mbuf + (size_t)BATCH * N_HEADS * SEQ_C;
  short* xb   = (short*)(lbuf + (size_t)BATCH * N_HEADS * SEQ_C); // residual (bf16)
  short* yb   = xb + (size_t)MQ * D_MODEL;                  // sublayer out (bf16)
  short* qb   = yb + (size_t)MQ * D_MODEL;
  short* kb   = qb + (size_t)MQ * D_MODEL;
  short* vb   = kb + (size_t)MQ * D_MODEL;
  short* ctxb = vb + (size_t)MQ * D_MODEL;
  short* hb   = qb;                                         // FFN hidden aliases qb..ctxb
  short* encb = ctxb + (size_t)MQ * D_MODEL;
  short* ckb  = encb + (size_t)MKV * D_MODEL;               // CA K (per-layer)
  short* cvb  = ckb + (size_t)MKV * D_MODEL;                // CA V (per-layer)
  short* wtb  = cvb + (size_t)MKV * D_MODEL;
  short* wts  = wtb + (size_t)128 * D_MODEL;
  const size_t WSZ = (size_t)NLAYER * D_MODEL * D_MODEL;
  short* w_saqkv = wts;
  short* w_sao   = w_saqkv + 3 * WSZ;
  short* w_caq   = w_sao + WSZ;
  short* w_cakv  = w_caq + WSZ;
  short* w_cao   = w_cakv + 2 * WSZ;
  short* w_ff1   = w_cao + WSZ;
  short* w_ff2   = w_ff1 + (size_t)NLAYER * D_MODEL * FFDIM;
  float* y2   = (float*)(w_ff2 + (size_t)NLAYER * D_MODEL * FFDIM); // dedicated 16MB

  float* logits = (float*)d_out;
  float* attn   = logits + (size_t)MQ * VOCAB;

  const size_t L1536 = (size_t)1536 * 512, L1024 = (size_t)1024 * 512, L512 = (size_t)512 * 512;

  // ---- prologue ----
  embed_kernel<<<MQ * D_MODEL / 1024, 256, 0, stream>>>(cds, tok_emb, pos_emb, xb);
  cvtf2b_kernel<<<(size_t)MKV * D_MODEL / 1024, 256, 0, stream>>>(enc_prot, encb);
  logits_wt_kernel<<<128 * D_MODEL / 256, 256, 0, stream>>>(fcw, wtb);
  {
    WtArgs a;
    a.src[0] = sa_wq; a.dst[0] = w_saqkv; a.ldz[0] = L1536; a.row_off[0] = 0;
    a.src[1] = sa_wk; a.dst[1] = w_saqkv; a.ldz[1] = L1536; a.row_off[1] = 512;
    a.src[2] = sa_wv; a.dst[2] = w_saqkv; a.ldz[2] = L1536; a.row_off[2] = 1024;
    a.src[3] = sa_wo; a.dst[3] = w_sao;   a.ldz[3] = L512;  a.row_off[3] = 0;
    a.src[4] = ca_wq; a.dst[4] = w_caq;   a.ldz[4] = L512;  a.row_off[4] = 0;
    a.src[5] = ca_wk; a.dst[5] = w_cakv;  a.ldz[5] = L1024; a.row_off[5] = 0;
    a.src[6] = ca_wv; a.dst[6] = w_cakv;  a.ldz[6] = L1024; a.row_off[6] = 512;
    a.src[7] = ca_wo; a.dst[7] = w_cao;   a.ldz[7] = L512;  a.row_off[7] = 0;
    wtrans8_kernel<<<dim3(16, 16, 8 * NLAYER), 256, 0, stream>>>(a);
  }
  wtrans_kernel<<<dim3(FFDIM / 32, D_MODEL / 32, NLAYER), 256, 0, stream>>>(
      ff_w1, w_ff1, D_MODEL, FFDIM, (size_t)FFDIM * 512);
  wtrans_kernel<<<dim3(D_MODEL / 32, FFDIM / 32, NLAYER), 256, 0, stream>>>(
      ff_w2, w_ff2, FFDIM, D_MODEL, (size_t)512 * FFDIM);

  dim3 gq64(MQ / 64, D_MODEL / 128);    // (128,4) MT=64
  dim3 gf1(MQ / 128, FFDIM / 128);      // (64,16) MT=128
  dim3 gff2(MQ / 128, D_MODEL / 128, 2);// (64,4,2) MT=128 split-K
  dim3 glg(MQ / 64, 1);                 // MT=64
  dim3 ga(SEQ_C / 128, BATCH * N_HEADS);    // flash: 128 Q-rows, 512 thr
  dim3 gap(SEQ_C / 64, BATCH * N_HEADS);

  for (int i = 0; i < NLAYER; i++) {
    size_t wo_ = (size_t)i * D_MODEL * D_MODEL, bo_ = (size_t)i * D_MODEL;
    size_t wf_ = (size_t)i * D_MODEL * FFDIM;
    // --- layer-start mega: SA QKV + CA KV ---
    gemm_mega<<<dim3(1024), 256, 0, stream>>>(
        xb, w_saqkv + (size_t)i * L1536, sa_bq + bo_, sa_bk + bo_, sa_bv + bo_, qb,
        encb, w_cakv + (size_t)i * L1024, ca_bk + bo_, ca_bv + bo_, ckb);
    flash_mfma<true,  false><<<ga, 512, 0, stream>>>(qb, kb, vb, ctxb, nullptr, nullptr, SEQ_C, SEQ_C);
    gemm_mfma<0,1,64><<<gq64, 256, 0, stream>>>(ctxb, w_sao + wo_,
        sa_bo + bo_, nullptr, nullptr, nullptr, nullptr, yb, 512, 512, 512, 0);
    add_ln_kernel<0><<<MQ / 4, 256, 0, stream>>>(xb, yb, nullptr, nullptr, ln1_g + bo_, ln1_b + bo_);
    // --- cross attention ---
    gemm_mfma<0,1,64><<<gq64, 256, 0, stream>>>(xb, w_caq + wo_,
        ca_bq + bo_, nullptr, nullptr, nullptr, nullptr, qb, 512, 512, 512, 0);
    if (i == NLAYER - 1) {
      flash_mfma<false, true><<<ga, 512, 0, stream>>>(qb, ckb, cvb, ctxb, mbuf, lbuf, SEQ_C, SEQ_P);
      attn_prob_mfma<<<gap, 256, 0, stream>>>(qb, ckb, mbuf, lbuf, attn);
    } else {
      flash_mfma<false, false><<<ga, 512, 0, stream>>>(qb, ckb, cvb, ctxb, nullptr, nullptr, SEQ_C, SEQ_P);
    }
    gemm_mfma<0,1,64><<<gq64, 256, 0, stream>>>(ctxb, w_cao + wo_,
        ca_bo + bo_, nullptr, nullptr, nullptr, nullptr, yb, 512, 512, 512, 0);
    add_ln_kernel<0><<<MQ / 4, 256, 0, stream>>>(xb, yb, nullptr, nullptr, ln2_g + bo_, ln2_b + bo_);
    // --- FFN (FF2 split-K2 -> y + y2, fp32 partials) ---
    gemm_mfma<1,1,128><<<gf1, 256, 0, stream>>>(xb, w_ff1 + wf_,
        ff_b1 + (size_t)i * FFDIM, nullptr, nullptr, nullptr, nullptr, hb, FFDIM, 512, FFDIM, 0);
    gemm_mfma<0,0,128,1><<<gff2, 256, 0, stream>>>(hb, w_ff2 + wf_,
        ff_b2 + bo_, nullptr, nullptr, y, y2, nullptr, 512, FFDIM, 512, 0);
    add_ln_kernel<1><<<MQ / 4, 256, 0, stream>>>(xb, nullptr, y, y2, ln3_g + bo_, ln3_b + bo_);
  }
  // --- logits via MFMA (padded N=128, write-guard 70) ---
  gemm_mfma<0,3,64><<<glg, 256, 0, stream>>>(xb, wtb,
      fcb, nullptr, nullptr, logits, nullptr, nullptr, 128, 512, VOCAB, 0);
}